// Round 8
// baseline (368.246 us; speedup 1.0000x reference)
//
#include <hip/hip_runtime.h>
#include <hip/hip_bf16.h>
#include <stdint.h>

typedef __bf16 bf16;
typedef __attribute__((ext_vector_type(8))) __bf16 bf16x8;
typedef __attribute__((ext_vector_type(4))) float f32x4;
typedef __attribute__((ext_vector_type(8))) unsigned short u16x8;

#define LDS_U32 __attribute__((address_space(3))) uint32_t
#define GLB_U32 const __attribute__((address_space(1))) uint32_t
#define GLOAD16(g, l) __builtin_amdgcn_global_load_lds((GLB_U32*)(g), (LDS_U32*)(l), 16, 0, 0)

#define DSR(dst, addr, OFFLIT) \
  asm volatile("ds_read_b128 %0, %1 offset:" OFFLIT : "=v"(dst) : "v"(addr))

#define WAIT_LGKM0() asm volatile("s_waitcnt lgkmcnt(0)")
#define WAIT_VM(n)   asm volatile("s_waitcnt vmcnt(" #n ")")

// ---------------- fused f32 -> bf16 convert (all 5 inputs, one launch) ----------------
__global__ __launch_bounds__(256) void cvt_all(const float* __restrict__ q,
                                               const float* __restrict__ wq,
                                               const float* __restrict__ wk,
                                               const float* __restrict__ wv,
                                               const float* __restrict__ wo,
                                               bf16* __restrict__ qb,
                                               bf16* __restrict__ W3,
                                               bf16* __restrict__ wob) {
  const int b = blockIdx.x;
  const float* src;
  bf16* dst;
  int within;
  if (b < 2048) { src = q; dst = qb; within = b; }
  else {
    const int seg = (b - 2048) >> 8;      // 0..3
    within = (b - 2048) & 255;
    if (seg == 0)      { src = wq; dst = W3; }
    else if (seg == 1) { src = wk; dst = W3 + 1048576; }
    else if (seg == 2) { src = wv; dst = W3 + 2097152; }
    else               { src = wo; dst = wob; }
  }
  const int off = within * 1024;
#pragma unroll
  for (int it = 0; it < 4; ++it) {
    const int j = off + it * 256 + threadIdx.x;
    float4 v = reinterpret_cast<const float4*>(src)[j];
    ushort4 o;
    o.x = __builtin_bit_cast(unsigned short, (bf16)v.x);
    o.y = __builtin_bit_cast(unsigned short, (bf16)v.y);
    o.z = __builtin_bit_cast(unsigned short, (bf16)v.z);
    o.w = __builtin_bit_cast(unsigned short, (bf16)v.w);
    reinterpret_cast<ushort4*>(dst)[j] = o;
  }
}

// ============ 256 x (WN*64) 8-phase GEMM, C = alpha * A @ B^T ============
// WN=4: 256x256 tile (r7 config, unchanged). WN=6: 256x384 tile -> QKV grid
// (8,32)=256 blocks = EXACTLY 1/CU (r7's 384-block grid left half the CUs
// running 2 blocks -> 2x wall time; grid balance is the fix, not occupancy).
// 512 thr = 8 waves (2Mx4N); per-wave 128 x WN*16 out, acc[8][WN].
// LDS: A 32KB (4 units x 8KB, 64 rows x 64k) + B WN*8KB. Single buffer.
// st_16x32 swizzle both-sides (linear gload dest + inv-swizzled global src).
// Ring (stages strictly after last-reader barrier): ph1: B(T+1) x WN;
// ph2: A{0,2}(T+1) x2; boundary: A{1,3}(T+1) x2.
// Waits: end-ph1 vmcnt(WN) retires A{1,3}(T); boundary vmcnt(2) retires
// B(T+1)+A{0,2}(T+1), leaves A{1,3}(T+1) in flight. Slack >= 1.5 phases.
template <int EPI, int WN>
__global__ __launch_bounds__(512, 2) void g256(const bf16* __restrict__ A,
                                               const bf16* __restrict__ Bm,
                                               void* __restrict__ Cp,
                                               int K, float alpha,
                                               long sA, long sB, long sC, int ldc) {
  constexpr int BN = WN * 64;
  __shared__ bf16 smem_[(32768 + WN * 8192) / 2];
  const long z = blockIdx.z;
  const int t = threadIdx.x;
  const int l = t & 63;
  const int w = t >> 6;
  const int wr = (w >> 2) * 128;        // wave row base within 256
  const int wc = (w & 3) * (WN * 16);   // wave col base within BN
  const int NT = K >> 6;

  const bf16* Ab = A + z * sA + (long)(blockIdx.y * 256) * K;
  const bf16* Bb = Bm + z * sB + (long)(blockIdx.x * BN) * K;

  // staging inverse map: thread t covers swizzled bytes [t*16, t*16+16) of one
  // 8KB 64-row unit; (r0,c0) = source row/col within the unit.
  uint32_t loc = (uint32_t)t * 16u;
  uint32_t g0 = loc ^ (((loc >> 9) & 1u) << 5);
  const int r0 = (int)(((g0 >> 10) >> 1) * 16 + ((g0 >> 6) & 15));  // 0..63
  const int c0 = (int)(((g0 >> 10) & 1) * 32 + ((g0 & 63) >> 1));   // 0..63

  // per-lane swizzled fragment read offset
  uint32_t lo_ = (uint32_t)((l & 15) * 64 + (l >> 4) * 16);
  const uint32_t lane_off = lo_ ^ (((lo_ >> 9) & 1u) << 5);
  const uint32_t aRegion = (uint32_t)(wr >> 7) * 16384u;
  const uint32_t smem_base = (uint32_t)(size_t)&smem_[0];
  const uint32_t aAddr = smem_base + aRegion + lane_off;

  // per-n B fragment base addresses (row = wc + n*16 within B panel)
  uint32_t bA[WN];
#pragma unroll
  for (int n = 0; n < WN; ++n) {
    const uint32_t row = (uint32_t)(wc + n * 16);
    bA[n] = smem_base + 32768u + (row >> 6) * 8192u + ((row & 63u) >> 4) * 2048u + lane_off;
  }

  auto STAGE1 = [&](const bf16* mat, int unit, int tile, uint32_t isB) {
    uint32_t dst = isB + (uint32_t)unit * 8192u + (uint32_t)t * 16u;
    const bf16* src = mat + (long)(unit * 64 + r0) * K + tile * 64 + c0;
    GLOAD16(src, smem_ + (dst >> 1));
  };

  f32x4 acc[8][WN] = {};

  // ---- prologue: A(0) + B(0) fully staged
  STAGE1(Ab, 0, 0, 0u); STAGE1(Ab, 1, 0, 0u); STAGE1(Ab, 2, 0, 0u); STAGE1(Ab, 3, 0, 0u);
#pragma unroll
  for (int u = 0; u < WN; ++u) STAGE1(Bb, u, 0, 32768u);
  __builtin_amdgcn_sched_barrier(0);
  WAIT_VM(0);
  __builtin_amdgcn_s_barrier();

#define MFMAPH(ph)                                                                   \
  _Pragma("unroll") for (int mi = 0; mi < 2; ++mi)                                   \
  _Pragma("unroll") for (int n = 0; n < WN; ++n)                                     \
  _Pragma("unroll") for (int kk = 0; kk < 2; ++kk)                                   \
    acc[(ph) * 2 + mi][n] = __builtin_amdgcn_mfma_f32_16x16x32_bf16(                 \
        __builtin_bit_cast(bf16x8, aF[mi][kk]), __builtin_bit_cast(bf16x8, bF[n][kk]), \
        acc[(ph) * 2 + mi][n], 0, 0, 0);

  for (int T = 0; T < NT; ++T) {
    f32x4 bF[WN][2];
    f32x4 aF[2][2];

    // ---------- phase 0: all bF (2*WN) + aF quad0 (4); no staging ----------
#pragma unroll
    for (int n = 0; n < WN; ++n) {
      DSR(bF[n][0], bA[n], "0");
      DSR(bF[n][1], bA[n], "1024");
    }
    DSR(aF[0][0], aAddr, "0");    DSR(aF[0][1], aAddr, "1024");
    DSR(aF[1][0], aAddr, "2048"); DSR(aF[1][1], aAddr, "3072");
    __builtin_amdgcn_sched_barrier(0);
    __builtin_amdgcn_s_barrier();
    WAIT_LGKM0();
    __builtin_amdgcn_sched_barrier(0);
    __builtin_amdgcn_s_setprio(1);
    MFMAPH(0)
    __builtin_amdgcn_s_setprio(0);
    __builtin_amdgcn_s_barrier();

    // ---------- phase 1: aF quad1; stage B(T+1); vmcnt(WN) retires A{1,3}(T) ----------
    {
      const uint32_t aP = aAddr + 4096u;
      DSR(aF[0][0], aP, "0");    DSR(aF[0][1], aP, "1024");
      DSR(aF[1][0], aP, "2048"); DSR(aF[1][1], aP, "3072");
      if (T + 1 < NT) {
#pragma unroll
        for (int u = 0; u < WN; ++u) STAGE1(Bb, u, T + 1, 32768u);
      }
      __builtin_amdgcn_sched_barrier(0);
      __builtin_amdgcn_s_barrier();
      WAIT_LGKM0();
      __builtin_amdgcn_sched_barrier(0);
      __builtin_amdgcn_s_setprio(1);
      MFMAPH(1)
      __builtin_amdgcn_s_setprio(0);
      __builtin_amdgcn_sched_barrier(0);
      if (T + 1 < NT) {
        if constexpr (WN == 4) { WAIT_VM(4); } else { WAIT_VM(6); }
      } else {
        WAIT_VM(0);
      }
      __builtin_amdgcn_sched_barrier(0);
      __builtin_amdgcn_s_barrier();
    }

    // ---------- phase 2: aF quad2; stage A{0,2}(T+1) ----------
    {
      const uint32_t aP = aAddr + 8192u;
      DSR(aF[0][0], aP, "0");    DSR(aF[0][1], aP, "1024");
      DSR(aF[1][0], aP, "2048"); DSR(aF[1][1], aP, "3072");
      if (T + 1 < NT) { STAGE1(Ab, 0, T + 1, 0u); STAGE1(Ab, 2, T + 1, 0u); }
      __builtin_amdgcn_sched_barrier(0);
      __builtin_amdgcn_s_barrier();
      WAIT_LGKM0();
      __builtin_amdgcn_sched_barrier(0);
      __builtin_amdgcn_s_setprio(1);
      MFMAPH(2)
      __builtin_amdgcn_s_setprio(0);
      __builtin_amdgcn_s_barrier();
    }

    // ---------- phase 3: aF quad3; no staging ----------
    {
      const uint32_t aP = aAddr + 12288u;
      DSR(aF[0][0], aP, "0");    DSR(aF[0][1], aP, "1024");
      DSR(aF[1][0], aP, "2048"); DSR(aF[1][1], aP, "3072");
      __builtin_amdgcn_sched_barrier(0);
      __builtin_amdgcn_s_barrier();
      WAIT_LGKM0();
      __builtin_amdgcn_sched_barrier(0);
      __builtin_amdgcn_s_setprio(1);
      MFMAPH(3)
      __builtin_amdgcn_s_setprio(0);
      __builtin_amdgcn_s_barrier();
    }

    // ---------- boundary: stage A{1,3}(T+1); vmcnt(2) ----------
    if (T + 1 < NT) { STAGE1(Ab, 1, T + 1, 0u); STAGE1(Ab, 3, T + 1, 0u); }
    __builtin_amdgcn_sched_barrier(0);
    if (T + 1 < NT) { WAIT_VM(2); } else { WAIT_VM(0); }
    __builtin_amdgcn_sched_barrier(0);
    __builtin_amdgcn_s_barrier();
  }
#undef MFMAPH

  // ---- epilogue: C/D layout col = lane&15, row = (lane>>4)*4 + i
  const int orow0 = blockIdx.y * 256 + wr + (l >> 4) * 4;
  const int ocol0 = blockIdx.x * BN + wc + (l & 15);
#pragma unroll
  for (int m = 0; m < 8; ++m)
#pragma unroll
    for (int n = 0; n < WN; ++n)
#pragma unroll
      for (int i = 0; i < 4; ++i) {
        const long r = orow0 + m * 16 + i;
        const long c = ocol0 + n * 16;
        const float v = acc[m][n][i] * alpha;
        if constexpr (EPI == 0) {
          ((bf16*)Cp)[z * sC + r * ldc + c] = (bf16)v;
        } else if constexpr (EPI == 2) {
          ((float*)Cp)[r * ldc + c] = v;
        } else {
          // fused QKV epilogue: rows r = b*2048+s in [0,8192); cols c in [0,3072)
          bf16* Qb = (bf16*)Cp;
          bf16* Kb = Qb + 8388608;  // 8192*1024
          bf16* Vt = Kb + 8388608;
          if (c < 1024) Qb[r * 1024 + c] = (bf16)v;
          else if (c < 2048) Kb[r * 1024 + (c - 1024)] = (bf16)v;
          else Vt[(r >> 11) * 2097152 + (c - 2048) * 2048 + (r & 2047)] = (bf16)v;
        }
      }
}

// ---------------- row softmax, in place, rows of 2048 bf16 ----------------
__global__ __launch_bounds__(256) void softmax_rows(bf16* __restrict__ P) {
  const long row = blockIdx.x;
  bf16* p = P + row * 2048;
  const int t = threadIdx.x;
  const int lane = t & 63;
  const int wave = t >> 6;

  u16x8 raw = *reinterpret_cast<const u16x8*>(p + t * 8);
  float v[8];
#pragma unroll
  for (int j = 0; j < 8; ++j) {
    uint32_t bits = ((uint32_t)raw[j]) << 16;
    v[j] = __builtin_bit_cast(float, bits);
  }
  float m = v[0];
#pragma unroll
  for (int j = 1; j < 8; ++j) m = fmaxf(m, v[j]);
#pragma unroll
  for (int off = 32; off > 0; off >>= 1) m = fmaxf(m, __shfl_xor(m, off, 64));
  __shared__ float redm[4];
  __shared__ float reds[4];
  if (lane == 0) redm[wave] = m;
  __syncthreads();
  m = fmaxf(fmaxf(redm[0], redm[1]), fmaxf(redm[2], redm[3]));

  float s = 0.f;
#pragma unroll
  for (int j = 0; j < 8; ++j) {
    v[j] = __expf(v[j] - m);
    s += v[j];
  }
#pragma unroll
  for (int off = 32; off > 0; off >>= 1) s += __shfl_xor(s, off, 64);
  if (lane == 0) reds[wave] = s;
  __syncthreads();
  s = reds[0] + reds[1] + reds[2] + reds[3];
  const float inv = 1.f / s;

  u16x8 o;
#pragma unroll
  for (int j = 0; j < 8; ++j) o[j] = __builtin_bit_cast(unsigned short, (bf16)(v[j] * inv));
  *reinterpret_cast<u16x8*>(p + t * 8) = o;
}

// ---------------- launch ----------------
extern "C" void kernel_launch(void* const* d_in, const int* in_sizes, int n_in,
                              void* d_out, int out_size, void* d_ws, size_t ws_size,
                              hipStream_t stream) {
  const float* q = (const float*)d_in[0];
  const float* wq = (const float*)d_in[1];
  const float* wk = (const float*)d_in[2];
  const float* wv = (const float*)d_in[3];
  const float* wo = (const float*)d_in[4];
  float* out = (float*)d_out;

  constexpr int B = 4, S = 2048, D = 1024;
  constexpr long SD = (long)S * D;  // 2,097,152
  constexpr long SS = (long)S * S;  // 4,194,304
  constexpr long DD = (long)D * D;  // 1,048,576

  bf16* wsb = (bf16*)d_ws;
  bf16* qb = wsb;             // B*SD
  bf16* W3 = qb + B * SD;     // 3*DD  (wq;wk;wv stacked rows)
  bf16* wob = W3 + 3 * DD;    // DD
  bf16* Qb = wob + DD;        // B*SD
  bf16* Kb = Qb + B * SD;     // B*SD
  bf16* Vt = Kb + B * SD;     // B*SD, layout [B][D][S]
  bf16* P = Vt + B * SD;      // B*SS
  bf16* X = P + B * SS;       // B*SD, layout [B][D][S] == bugged buffer

  cvt_all<<<3072, 256, 0, stream>>>(q, wq, wk, wv, wo, qb, W3, wob);

  // fused QKV: [8192 x 1024] @ [3072 x 1024]^T -> Qb, Kb, Vt(transposed)
  // 256x384 tile => grid (8,32) = 256 blocks = exactly 1/CU (balance fix).
  g256<3, 6><<<dim3(8, 32, 1), 512, 0, stream>>>(qb, W3, Qb, D, 1.f, 0, 0, 0, 0);
  // scores: P[b][i][j] = Q.K/8  (per batch 2048x2048, K=1024), 256 blocks
  g256<0, 4><<<dim3(8, 8, B), 512, 0, stream>>>(Qb, Kb, P, D, 0.125f, SD, SD, SS, S);
  softmax_rows<<<B * S, 256, 0, stream>>>(P);
  // PV as Xt = Vt @ P^T: C[e][i] = sum_j Vt[e][j] P[i][j]  (M=1024, N=2048, K=2048)
  g256<0, 4><<<dim3(8, 4, B), 512, 0, stream>>>(Vt, P, X, S, 1.f, SD, SS, SD, S);
  // out = Xflat[8192x1024] @ wo^T -> f32
  g256<2, 4><<<dim3(4, 32, 1), 512, 0, stream>>>(X, wob, out, D, 1.f, 0, 0, 0, D);
}

// Round 9
// 245.226 us; speedup vs baseline: 1.5017x; 1.5017x over previous
//
#include <hip/hip_runtime.h>
#include <hip/hip_bf16.h>
#include <stdint.h>

typedef __bf16 bf16;
typedef __attribute__((ext_vector_type(8))) __bf16 bf16x8;
typedef __attribute__((ext_vector_type(4))) float f32x4;
typedef __attribute__((ext_vector_type(8))) unsigned short u16x8;

#define LDS_U32 __attribute__((address_space(3))) uint32_t
#define GLB_U32 const __attribute__((address_space(1))) uint32_t
#define GLOAD16(g, l) __builtin_amdgcn_global_load_lds((GLB_U32*)(g), (LDS_U32*)(l), 16, 0, 0)

#define DSR(dst, addr, OFFLIT) \
  asm volatile("ds_read_b128 %0, %1 offset:" OFFLIT : "=v"(dst) : "v"(addr))

#define WAIT_LGKM0() asm volatile("s_waitcnt lgkmcnt(0)")
#define WAIT_VM(n)   asm volatile("s_waitcnt vmcnt(" #n ")")

// ---------------- fused f32 -> bf16 convert (all 5 inputs, one launch) ----------------
__global__ __launch_bounds__(256) void cvt_all(const float* __restrict__ q,
                                               const float* __restrict__ wq,
                                               const float* __restrict__ wk,
                                               const float* __restrict__ wv,
                                               const float* __restrict__ wo,
                                               bf16* __restrict__ qb,
                                               bf16* __restrict__ W3,
                                               bf16* __restrict__ wob) {
  const int b = blockIdx.x;
  const float* src;
  bf16* dst;
  int within;
  if (b < 2048) { src = q; dst = qb; within = b; }
  else {
    const int seg = (b - 2048) >> 8;      // 0..3
    within = (b - 2048) & 255;
    if (seg == 0)      { src = wq; dst = W3; }
    else if (seg == 1) { src = wk; dst = W3 + 1048576; }
    else if (seg == 2) { src = wv; dst = W3 + 2097152; }
    else               { src = wo; dst = wob; }
  }
  const int off = within * 1024;
#pragma unroll
  for (int it = 0; it < 4; ++it) {
    const int j = off + it * 256 + threadIdx.x;
    float4 v = reinterpret_cast<const float4*>(src)[j];
    ushort4 o;
    o.x = __builtin_bit_cast(unsigned short, (bf16)v.x);
    o.y = __builtin_bit_cast(unsigned short, (bf16)v.y);
    o.z = __builtin_bit_cast(unsigned short, (bf16)v.z);
    o.w = __builtin_bit_cast(unsigned short, (bf16)v.w);
    reinterpret_cast<ushort4*>(dst)[j] = o;
  }
}

// ============ 256 x (WN*64) 8-phase GEMM, C = alpha * A @ B^T ============
// WN=4: 256x256 (r7-proven). WN=3: 256x192 -> QKV grid (16,32) = 512 blocks
// = exactly 2/CU (balanced). WN=6 (r8) spilled: 192 acc + 48 bF + 16 aF
// crossed the 256-VGPR line -> 445MB scratch writes. WN=3 SHRINKS registers
// vs WN=4 (acc 96): same balance fix, zero spill risk.
// 512 thr = 8 waves (2Mx4N); per-wave 128 x WN*16 out, acc[8][WN].
// LDS: A 32KB (4 units x 8KB, 64 rows x 64k) + B WN*8KB. Single buffer.
// st_16x32 swizzle both-sides (linear gload dest + inv-swizzled global src).
// Ring (stages strictly after last-reader barrier): ph1: B(T+1) x WN;
// ph2: A{0,2}(T+1) x2; boundary: A{1,3}(T+1) x2.
// Waits: end-ph1 vmcnt(WN) retires A{1,3}(T); boundary vmcnt(2) retires
// B(T+1)+A{0,2}(T+1), leaves A{1,3}(T+1) in flight.
template <int EPI, int WN>
__global__ __launch_bounds__(512, 2) void g256(const bf16* __restrict__ A,
                                               const bf16* __restrict__ Bm,
                                               void* __restrict__ Cp,
                                               int K, float alpha,
                                               long sA, long sB, long sC, int ldc) {
  constexpr int BN = WN * 64;
  __shared__ bf16 smem_[(32768 + WN * 8192) / 2];
  const long z = blockIdx.z;
  const int t = threadIdx.x;
  const int l = t & 63;
  const int w = t >> 6;
  const int wr = (w >> 2) * 128;        // wave row base within 256
  const int wc = (w & 3) * (WN * 16);   // wave col base within BN
  const int NT = K >> 6;

  const bf16* Ab = A + z * sA + (long)(blockIdx.y * 256) * K;
  const bf16* Bb = Bm + z * sB + (long)(blockIdx.x * BN) * K;

  // staging inverse map: thread t covers swizzled bytes [t*16, t*16+16) of one
  // 8KB 64-row unit; (r0,c0) = source row/col within the unit.
  uint32_t loc = (uint32_t)t * 16u;
  uint32_t g0 = loc ^ (((loc >> 9) & 1u) << 5);
  const int r0 = (int)(((g0 >> 10) >> 1) * 16 + ((g0 >> 6) & 15));  // 0..63
  const int c0 = (int)(((g0 >> 10) & 1) * 32 + ((g0 & 63) >> 1));   // 0..63

  // per-lane swizzled fragment read offset
  uint32_t lo_ = (uint32_t)((l & 15) * 64 + (l >> 4) * 16);
  const uint32_t lane_off = lo_ ^ (((lo_ >> 9) & 1u) << 5);
  const uint32_t aRegion = (uint32_t)(wr >> 7) * 16384u;
  const uint32_t smem_base = (uint32_t)(size_t)&smem_[0];
  const uint32_t aAddr = smem_base + aRegion + lane_off;

  // per-n B fragment base addresses (row = wc + n*16 within B panel)
  uint32_t bA[WN];
#pragma unroll
  for (int n = 0; n < WN; ++n) {
    const uint32_t row = (uint32_t)(wc + n * 16);
    bA[n] = smem_base + 32768u + (row >> 6) * 8192u + ((row & 63u) >> 4) * 2048u + lane_off;
  }

  auto STAGE1 = [&](const bf16* mat, int unit, int tile, uint32_t isB) {
    uint32_t dst = isB + (uint32_t)unit * 8192u + (uint32_t)t * 16u;
    const bf16* src = mat + (long)(unit * 64 + r0) * K + tile * 64 + c0;
    GLOAD16(src, smem_ + (dst >> 1));
  };

  f32x4 acc[8][WN] = {};

  // ---- prologue: A(0) + B(0) fully staged
  STAGE1(Ab, 0, 0, 0u); STAGE1(Ab, 1, 0, 0u); STAGE1(Ab, 2, 0, 0u); STAGE1(Ab, 3, 0, 0u);
#pragma unroll
  for (int u = 0; u < WN; ++u) STAGE1(Bb, u, 0, 32768u);
  __builtin_amdgcn_sched_barrier(0);
  WAIT_VM(0);
  __builtin_amdgcn_s_barrier();

#define MFMAPH(ph)                                                                   \
  _Pragma("unroll") for (int mi = 0; mi < 2; ++mi)                                   \
  _Pragma("unroll") for (int n = 0; n < WN; ++n)                                     \
  _Pragma("unroll") for (int kk = 0; kk < 2; ++kk)                                   \
    acc[(ph) * 2 + mi][n] = __builtin_amdgcn_mfma_f32_16x16x32_bf16(                 \
        __builtin_bit_cast(bf16x8, aF[mi][kk]), __builtin_bit_cast(bf16x8, bF[n][kk]), \
        acc[(ph) * 2 + mi][n], 0, 0, 0);

  for (int T = 0; T < NT; ++T) {
    f32x4 bF[WN][2];
    f32x4 aF[2][2];

    // ---------- phase 0: all bF (2*WN) + aF quad0 (4); no staging ----------
#pragma unroll
    for (int n = 0; n < WN; ++n) {
      DSR(bF[n][0], bA[n], "0");
      DSR(bF[n][1], bA[n], "1024");
    }
    DSR(aF[0][0], aAddr, "0");    DSR(aF[0][1], aAddr, "1024");
    DSR(aF[1][0], aAddr, "2048"); DSR(aF[1][1], aAddr, "3072");
    __builtin_amdgcn_sched_barrier(0);
    __builtin_amdgcn_s_barrier();
    WAIT_LGKM0();
    __builtin_amdgcn_sched_barrier(0);
    __builtin_amdgcn_s_setprio(1);
    MFMAPH(0)
    __builtin_amdgcn_s_setprio(0);
    __builtin_amdgcn_s_barrier();

    // ---------- phase 1: aF quad1; stage B(T+1); vmcnt(WN) retires A{1,3}(T) ----------
    {
      const uint32_t aP = aAddr + 4096u;
      DSR(aF[0][0], aP, "0");    DSR(aF[0][1], aP, "1024");
      DSR(aF[1][0], aP, "2048"); DSR(aF[1][1], aP, "3072");
      if (T + 1 < NT) {
#pragma unroll
        for (int u = 0; u < WN; ++u) STAGE1(Bb, u, T + 1, 32768u);
      }
      __builtin_amdgcn_sched_barrier(0);
      __builtin_amdgcn_s_barrier();
      WAIT_LGKM0();
      __builtin_amdgcn_sched_barrier(0);
      __builtin_amdgcn_s_setprio(1);
      MFMAPH(1)
      __builtin_amdgcn_s_setprio(0);
      __builtin_amdgcn_sched_barrier(0);
      if (T + 1 < NT) {
        if constexpr (WN == 3) { WAIT_VM(3); }
        else if constexpr (WN == 4) { WAIT_VM(4); }
        else { WAIT_VM(6); }
      } else {
        WAIT_VM(0);
      }
      __builtin_amdgcn_sched_barrier(0);
      __builtin_amdgcn_s_barrier();
    }

    // ---------- phase 2: aF quad2; stage A{0,2}(T+1) ----------
    {
      const uint32_t aP = aAddr + 8192u;
      DSR(aF[0][0], aP, "0");    DSR(aF[0][1], aP, "1024");
      DSR(aF[1][0], aP, "2048"); DSR(aF[1][1], aP, "3072");
      if (T + 1 < NT) { STAGE1(Ab, 0, T + 1, 0u); STAGE1(Ab, 2, T + 1, 0u); }
      __builtin_amdgcn_sched_barrier(0);
      __builtin_amdgcn_s_barrier();
      WAIT_LGKM0();
      __builtin_amdgcn_sched_barrier(0);
      __builtin_amdgcn_s_setprio(1);
      MFMAPH(2)
      __builtin_amdgcn_s_setprio(0);
      __builtin_amdgcn_s_barrier();
    }

    // ---------- phase 3: aF quad3; no staging ----------
    {
      const uint32_t aP = aAddr + 12288u;
      DSR(aF[0][0], aP, "0");    DSR(aF[0][1], aP, "1024");
      DSR(aF[1][0], aP, "2048"); DSR(aF[1][1], aP, "3072");
      __builtin_amdgcn_sched_barrier(0);
      __builtin_amdgcn_s_barrier();
      WAIT_LGKM0();
      __builtin_amdgcn_sched_barrier(0);
      __builtin_amdgcn_s_setprio(1);
      MFMAPH(3)
      __builtin_amdgcn_s_setprio(0);
      __builtin_amdgcn_s_barrier();
    }

    // ---------- boundary: stage A{1,3}(T+1); vmcnt(2) ----------
    if (T + 1 < NT) { STAGE1(Ab, 1, T + 1, 0u); STAGE1(Ab, 3, T + 1, 0u); }
    __builtin_amdgcn_sched_barrier(0);
    if (T + 1 < NT) { WAIT_VM(2); } else { WAIT_VM(0); }
    __builtin_amdgcn_sched_barrier(0);
    __builtin_amdgcn_s_barrier();
  }
#undef MFMAPH

  // ---- epilogue: C/D layout col = lane&15, row = (lane>>4)*4 + i
  const int orow0 = blockIdx.y * 256 + wr + (l >> 4) * 4;
  const int ocol0 = blockIdx.x * BN + wc + (l & 15);
#pragma unroll
  for (int m = 0; m < 8; ++m)
#pragma unroll
    for (int n = 0; n < WN; ++n)
#pragma unroll
      for (int i = 0; i < 4; ++i) {
        const long r = orow0 + m * 16 + i;
        const long c = ocol0 + n * 16;
        const float v = acc[m][n][i] * alpha;
        if constexpr (EPI == 0) {
          ((bf16*)Cp)[z * sC + r * ldc + c] = (bf16)v;
        } else if constexpr (EPI == 2) {
          ((float*)Cp)[r * ldc + c] = v;
        } else {
          // fused QKV epilogue: rows r = b*2048+s in [0,8192); cols c in [0,3072)
          bf16* Qb = (bf16*)Cp;
          bf16* Kb = Qb + 8388608;  // 8192*1024
          bf16* Vt = Kb + 8388608;
          if (c < 1024) Qb[r * 1024 + c] = (bf16)v;
          else if (c < 2048) Kb[r * 1024 + (c - 1024)] = (bf16)v;
          else Vt[(r >> 11) * 2097152 + (c - 2048) * 2048 + (r & 2047)] = (bf16)v;
        }
      }
}

// ---------------- row softmax, in place, rows of 2048 bf16 ----------------
__global__ __launch_bounds__(256) void softmax_rows(bf16* __restrict__ P) {
  const long row = blockIdx.x;
  bf16* p = P + row * 2048;
  const int t = threadIdx.x;
  const int lane = t & 63;
  const int wave = t >> 6;

  u16x8 raw = *reinterpret_cast<const u16x8*>(p + t * 8);
  float v[8];
#pragma unroll
  for (int j = 0; j < 8; ++j) {
    uint32_t bits = ((uint32_t)raw[j]) << 16;
    v[j] = __builtin_bit_cast(float, bits);
  }
  float m = v[0];
#pragma unroll
  for (int j = 1; j < 8; ++j) m = fmaxf(m, v[j]);
#pragma unroll
  for (int off = 32; off > 0; off >>= 1) m = fmaxf(m, __shfl_xor(m, off, 64));
  __shared__ float redm[4];
  __shared__ float reds[4];
  if (lane == 0) redm[wave] = m;
  __syncthreads();
  m = fmaxf(fmaxf(redm[0], redm[1]), fmaxf(redm[2], redm[3]));

  float s = 0.f;
#pragma unroll
  for (int j = 0; j < 8; ++j) {
    v[j] = __expf(v[j] - m);
    s += v[j];
  }
#pragma unroll
  for (int off = 32; off > 0; off >>= 1) s += __shfl_xor(s, off, 64);
  if (lane == 0) reds[wave] = s;
  __syncthreads();
  s = reds[0] + reds[1] + reds[2] + reds[3];
  const float inv = 1.f / s;

  u16x8 o;
#pragma unroll
  for (int j = 0; j < 8; ++j) o[j] = __builtin_bit_cast(unsigned short, (bf16)(v[j] * inv));
  *reinterpret_cast<u16x8*>(p + t * 8) = o;
}

// ---------------- launch ----------------
extern "C" void kernel_launch(void* const* d_in, const int* in_sizes, int n_in,
                              void* d_out, int out_size, void* d_ws, size_t ws_size,
                              hipStream_t stream) {
  const float* q = (const float*)d_in[0];
  const float* wq = (const float*)d_in[1];
  const float* wk = (const float*)d_in[2];
  const float* wv = (const float*)d_in[3];
  const float* wo = (const float*)d_in[4];
  float* out = (float*)d_out;

  constexpr int B = 4, S = 2048, D = 1024;
  constexpr long SD = (long)S * D;  // 2,097,152
  constexpr long SS = (long)S * S;  // 4,194,304
  constexpr long DD = (long)D * D;  // 1,048,576

  bf16* wsb = (bf16*)d_ws;
  bf16* qb = wsb;             // B*SD
  bf16* W3 = qb + B * SD;     // 3*DD  (wq;wk;wv stacked rows)
  bf16* wob = W3 + 3 * DD;    // DD
  bf16* Qb = wob + DD;        // B*SD
  bf16* Kb = Qb + B * SD;     // B*SD
  bf16* Vt = Kb + B * SD;     // B*SD, layout [B][D][S]
  bf16* P = Vt + B * SD;      // B*SS
  bf16* X = P + B * SS;       // B*SD, layout [B][D][S] == bugged buffer

  cvt_all<<<3072, 256, 0, stream>>>(q, wq, wk, wv, wo, qb, W3, wob);

  // fused QKV: [8192 x 1024] @ [3072 x 1024]^T -> Qb, Kb, Vt(transposed)
  // 256x192 tile => grid (16,32) = 512 blocks = exactly 2/CU (balanced, no spill).
  g256<3, 3><<<dim3(16, 32, 1), 512, 0, stream>>>(qb, W3, Qb, D, 1.f, 0, 0, 0, 0);
  // scores: P[b][i][j] = Q.K/8  (per batch 2048x2048, K=1024), 256 blocks
  g256<0, 4><<<dim3(8, 8, B), 512, 0, stream>>>(Qb, Kb, P, D, 0.125f, SD, SD, SS, S);
  softmax_rows<<<B * S, 256, 0, stream>>>(P);
  // PV as Xt = Vt @ P^T: C[e][i] = sum_j Vt[e][j] P[i][j]  (M=1024, N=2048, K=2048)
  g256<0, 4><<<dim3(8, 4, B), 512, 0, stream>>>(Vt, P, X, S, 1.f, SD, SS, SD, S);
  // out = Xflat[8192x1024] @ wo^T -> f32
  g256<2, 4><<<dim3(4, 32, 1), 512, 0, stream>>>(X, wob, out, D, 1.f, 0, 0, 0, D);
}

// Round 10
// 223.426 us; speedup vs baseline: 1.6482x; 1.0976x over previous
//
#include <hip/hip_runtime.h>
#include <hip/hip_bf16.h>
#include <stdint.h>

typedef __bf16 bf16;
typedef __attribute__((ext_vector_type(8))) __bf16 bf16x8;
typedef __attribute__((ext_vector_type(4))) float f32x4;
typedef __attribute__((ext_vector_type(8))) unsigned short u16x8;

#define LDS_U32 __attribute__((address_space(3))) uint32_t
#define GLB_U32 const __attribute__((address_space(1))) uint32_t
#define GLOAD16(g, l) __builtin_amdgcn_global_load_lds((GLB_U32*)(g), (LDS_U32*)(l), 16, 0, 0)

#define DSR(dst, addr, OFFLIT) \
  asm volatile("ds_read_b128 %0, %1 offset:" OFFLIT : "=v"(dst) : "v"(addr))

#define WAIT_LGKM0() asm volatile("s_waitcnt lgkmcnt(0)")
#define WAIT_VM(n)   asm volatile("s_waitcnt vmcnt(" #n ")")

// ---------------- fused f32 -> bf16 convert (all 5 inputs, one launch) ----------------
__global__ __launch_bounds__(256) void cvt_all(const float* __restrict__ q,
                                               const float* __restrict__ wq,
                                               const float* __restrict__ wk,
                                               const float* __restrict__ wv,
                                               const float* __restrict__ wo,
                                               bf16* __restrict__ qb,
                                               bf16* __restrict__ W3,
                                               bf16* __restrict__ wob) {
  const int b = blockIdx.x;
  const float* src;
  bf16* dst;
  int within;
  if (b < 2048) { src = q; dst = qb; within = b; }
  else {
    const int seg = (b - 2048) >> 8;      // 0..3
    within = (b - 2048) & 255;
    if (seg == 0)      { src = wq; dst = W3; }
    else if (seg == 1) { src = wk; dst = W3 + 1048576; }
    else if (seg == 2) { src = wv; dst = W3 + 2097152; }
    else               { src = wo; dst = wob; }
  }
  const int off = within * 1024;
#pragma unroll
  for (int it = 0; it < 4; ++it) {
    const int j = off + it * 256 + threadIdx.x;
    float4 v = reinterpret_cast<const float4*>(src)[j];
    ushort4 o;
    o.x = __builtin_bit_cast(unsigned short, (bf16)v.x);
    o.y = __builtin_bit_cast(unsigned short, (bf16)v.y);
    o.z = __builtin_bit_cast(unsigned short, (bf16)v.z);
    o.w = __builtin_bit_cast(unsigned short, (bf16)v.w);
    reinterpret_cast<ushort4*>(dst)[j] = o;
  }
}

// ============ 256 x (WN*64) 8-phase GEMM, C = alpha * A @ B^T ============
// Grid balance is the primary lever (r9 analysis: per-CU rate ~4.1-4.5 TF is
// nearly independent of blocks/CU, so wall time = work / (CUs actually used)):
//   WN=4: 256x256 (scores: 256 blocks = 1/CU).
//   WN=3: 256x192 (r9 QKV config, 512 = 2/CU).
//   WN=2: 256x128 (QKV 768 = 3/CU; PV 256 = 1/CU; outproj 256 = 1/CU).
// r8's WN=6 spilled (445MB scratch); WN<=4 keeps acc+frags well under the cliff.
// 512 thr = 8 waves (2Mx4N); per-wave 128 x WN*16 out, acc[8][WN].
// LDS: A 32KB (4 units x 8KB, 64 rows x 64k) + B WN*8KB. Single buffer.
// st_16x32 swizzle both-sides (linear gload dest + inv-swizzled global src).
// Ring (stages strictly after last-reader barrier): ph1: B(T+1) x WN;
// ph2: A{0,2}(T+1) x2; boundary: A{1,3}(T+1) x2.
// Waits: end-ph1 vmcnt(WN) retires A{1,3}(T); boundary vmcnt(2) retires
// B(T+1)+A{0,2}(T+1) (WN-independent), leaves A{1,3}(T+1) in flight.
template <int EPI, int WN>
__global__ __launch_bounds__(512, 2) void g256(const bf16* __restrict__ A,
                                               const bf16* __restrict__ Bm,
                                               void* __restrict__ Cp,
                                               int K, float alpha,
                                               long sA, long sB, long sC, int ldc) {
  constexpr int BN = WN * 64;
  __shared__ bf16 smem_[(32768 + WN * 8192) / 2];
  const long z = blockIdx.z;
  const int t = threadIdx.x;
  const int l = t & 63;
  const int w = t >> 6;
  const int wr = (w >> 2) * 128;        // wave row base within 256
  const int wc = (w & 3) * (WN * 16);   // wave col base within BN
  const int NT = K >> 6;

  const bf16* Ab = A + z * sA + (long)(blockIdx.y * 256) * K;
  const bf16* Bb = Bm + z * sB + (long)(blockIdx.x * BN) * K;

  // staging inverse map: thread t covers swizzled bytes [t*16, t*16+16) of one
  // 8KB 64-row unit; (r0,c0) = source row/col within the unit.
  uint32_t loc = (uint32_t)t * 16u;
  uint32_t g0 = loc ^ (((loc >> 9) & 1u) << 5);
  const int r0 = (int)(((g0 >> 10) >> 1) * 16 + ((g0 >> 6) & 15));  // 0..63
  const int c0 = (int)(((g0 >> 10) & 1) * 32 + ((g0 & 63) >> 1));   // 0..63

  // per-lane swizzled fragment read offset
  uint32_t lo_ = (uint32_t)((l & 15) * 64 + (l >> 4) * 16);
  const uint32_t lane_off = lo_ ^ (((lo_ >> 9) & 1u) << 5);
  const uint32_t aRegion = (uint32_t)(wr >> 7) * 16384u;
  const uint32_t smem_base = (uint32_t)(size_t)&smem_[0];
  const uint32_t aAddr = smem_base + aRegion + lane_off;

  // per-n B fragment base addresses (row = wc + n*16 within B panel)
  uint32_t bA[WN];
#pragma unroll
  for (int n = 0; n < WN; ++n) {
    const uint32_t row = (uint32_t)(wc + n * 16);
    bA[n] = smem_base + 32768u + (row >> 6) * 8192u + ((row & 63u) >> 4) * 2048u + lane_off;
  }

  auto STAGE1 = [&](const bf16* mat, int unit, int tile, uint32_t isB) {
    uint32_t dst = isB + (uint32_t)unit * 8192u + (uint32_t)t * 16u;
    const bf16* src = mat + (long)(unit * 64 + r0) * K + tile * 64 + c0;
    GLOAD16(src, smem_ + (dst >> 1));
  };

  f32x4 acc[8][WN] = {};

  // ---- prologue: A(0) + B(0) fully staged
  STAGE1(Ab, 0, 0, 0u); STAGE1(Ab, 1, 0, 0u); STAGE1(Ab, 2, 0, 0u); STAGE1(Ab, 3, 0, 0u);
#pragma unroll
  for (int u = 0; u < WN; ++u) STAGE1(Bb, u, 0, 32768u);
  __builtin_amdgcn_sched_barrier(0);
  WAIT_VM(0);
  __builtin_amdgcn_s_barrier();

#define MFMAPH(ph)                                                                   \
  _Pragma("unroll") for (int mi = 0; mi < 2; ++mi)                                   \
  _Pragma("unroll") for (int n = 0; n < WN; ++n)                                     \
  _Pragma("unroll") for (int kk = 0; kk < 2; ++kk)                                   \
    acc[(ph) * 2 + mi][n] = __builtin_amdgcn_mfma_f32_16x16x32_bf16(                 \
        __builtin_bit_cast(bf16x8, aF[mi][kk]), __builtin_bit_cast(bf16x8, bF[n][kk]), \
        acc[(ph) * 2 + mi][n], 0, 0, 0);

  for (int T = 0; T < NT; ++T) {
    f32x4 bF[WN][2];
    f32x4 aF[2][2];

    // ---------- phase 0: all bF (2*WN) + aF quad0 (4); no staging ----------
#pragma unroll
    for (int n = 0; n < WN; ++n) {
      DSR(bF[n][0], bA[n], "0");
      DSR(bF[n][1], bA[n], "1024");
    }
    DSR(aF[0][0], aAddr, "0");    DSR(aF[0][1], aAddr, "1024");
    DSR(aF[1][0], aAddr, "2048"); DSR(aF[1][1], aAddr, "3072");
    __builtin_amdgcn_sched_barrier(0);
    __builtin_amdgcn_s_barrier();
    WAIT_LGKM0();
    __builtin_amdgcn_sched_barrier(0);
    __builtin_amdgcn_s_setprio(1);
    MFMAPH(0)
    __builtin_amdgcn_s_setprio(0);
    __builtin_amdgcn_s_barrier();

    // ---------- phase 1: aF quad1; stage B(T+1); vmcnt(WN) retires A{1,3}(T) ----------
    {
      const uint32_t aP = aAddr + 4096u;
      DSR(aF[0][0], aP, "0");    DSR(aF[0][1], aP, "1024");
      DSR(aF[1][0], aP, "2048"); DSR(aF[1][1], aP, "3072");
      if (T + 1 < NT) {
#pragma unroll
        for (int u = 0; u < WN; ++u) STAGE1(Bb, u, T + 1, 32768u);
      }
      __builtin_amdgcn_sched_barrier(0);
      __builtin_amdgcn_s_barrier();
      WAIT_LGKM0();
      __builtin_amdgcn_sched_barrier(0);
      __builtin_amdgcn_s_setprio(1);
      MFMAPH(1)
      __builtin_amdgcn_s_setprio(0);
      __builtin_amdgcn_sched_barrier(0);
      if (T + 1 < NT) {
        if constexpr (WN == 2) { WAIT_VM(2); }
        else if constexpr (WN == 3) { WAIT_VM(3); }
        else { WAIT_VM(4); }
      } else {
        WAIT_VM(0);
      }
      __builtin_amdgcn_sched_barrier(0);
      __builtin_amdgcn_s_barrier();
    }

    // ---------- phase 2: aF quad2; stage A{0,2}(T+1) ----------
    {
      const uint32_t aP = aAddr + 8192u;
      DSR(aF[0][0], aP, "0");    DSR(aF[0][1], aP, "1024");
      DSR(aF[1][0], aP, "2048"); DSR(aF[1][1], aP, "3072");
      if (T + 1 < NT) { STAGE1(Ab, 0, T + 1, 0u); STAGE1(Ab, 2, T + 1, 0u); }
      __builtin_amdgcn_sched_barrier(0);
      __builtin_amdgcn_s_barrier();
      WAIT_LGKM0();
      __builtin_amdgcn_sched_barrier(0);
      __builtin_amdgcn_s_setprio(1);
      MFMAPH(2)
      __builtin_amdgcn_s_setprio(0);
      __builtin_amdgcn_s_barrier();
    }

    // ---------- phase 3: aF quad3; no staging ----------
    {
      const uint32_t aP = aAddr + 12288u;
      DSR(aF[0][0], aP, "0");    DSR(aF[0][1], aP, "1024");
      DSR(aF[1][0], aP, "2048"); DSR(aF[1][1], aP, "3072");
      __builtin_amdgcn_sched_barrier(0);
      __builtin_amdgcn_s_barrier();
      WAIT_LGKM0();
      __builtin_amdgcn_sched_barrier(0);
      __builtin_amdgcn_s_setprio(1);
      MFMAPH(3)
      __builtin_amdgcn_s_setprio(0);
      __builtin_amdgcn_s_barrier();
    }

    // ---------- boundary: stage A{1,3}(T+1); vmcnt(2) ----------
    if (T + 1 < NT) { STAGE1(Ab, 1, T + 1, 0u); STAGE1(Ab, 3, T + 1, 0u); }
    __builtin_amdgcn_sched_barrier(0);
    if (T + 1 < NT) { WAIT_VM(2); } else { WAIT_VM(0); }
    __builtin_amdgcn_sched_barrier(0);
    __builtin_amdgcn_s_barrier();
  }
#undef MFMAPH

  // ---- epilogue: C/D layout col = lane&15, row = (lane>>4)*4 + i
  const int orow0 = blockIdx.y * 256 + wr + (l >> 4) * 4;
  const int ocol0 = blockIdx.x * BN + wc + (l & 15);
#pragma unroll
  for (int m = 0; m < 8; ++m)
#pragma unroll
    for (int n = 0; n < WN; ++n)
#pragma unroll
      for (int i = 0; i < 4; ++i) {
        const long r = orow0 + m * 16 + i;
        const long c = ocol0 + n * 16;
        const float v = acc[m][n][i] * alpha;
        if constexpr (EPI == 0) {
          ((bf16*)Cp)[z * sC + r * ldc + c] = (bf16)v;
        } else if constexpr (EPI == 2) {
          ((float*)Cp)[r * ldc + c] = v;
        } else {
          // fused QKV epilogue: rows r = b*2048+s in [0,8192); cols c in [0,3072)
          bf16* Qb = (bf16*)Cp;
          bf16* Kb = Qb + 8388608;  // 8192*1024
          bf16* Vt = Kb + 8388608;
          if (c < 1024) Qb[r * 1024 + c] = (bf16)v;
          else if (c < 2048) Kb[r * 1024 + (c - 1024)] = (bf16)v;
          else Vt[(r >> 11) * 2097152 + (c - 2048) * 2048 + (r & 2047)] = (bf16)v;
        }
      }
}

// ---------------- row softmax, in place, rows of 2048 bf16 ----------------
__global__ __launch_bounds__(256) void softmax_rows(bf16* __restrict__ P) {
  const long row = blockIdx.x;
  bf16* p = P + row * 2048;
  const int t = threadIdx.x;
  const int lane = t & 63;
  const int wave = t >> 6;

  u16x8 raw = *reinterpret_cast<const u16x8*>(p + t * 8);
  float v[8];
#pragma unroll
  for (int j = 0; j < 8; ++j) {
    uint32_t bits = ((uint32_t)raw[j]) << 16;
    v[j] = __builtin_bit_cast(float, bits);
  }
  float m = v[0];
#pragma unroll
  for (int j = 1; j < 8; ++j) m = fmaxf(m, v[j]);
#pragma unroll
  for (int off = 32; off > 0; off >>= 1) m = fmaxf(m, __shfl_xor(m, off, 64));
  __shared__ float redm[4];
  __shared__ float reds[4];
  if (lane == 0) redm[wave] = m;
  __syncthreads();
  m = fmaxf(fmaxf(redm[0], redm[1]), fmaxf(redm[2], redm[3]));

  float s = 0.f;
#pragma unroll
  for (int j = 0; j < 8; ++j) {
    v[j] = __expf(v[j] - m);
    s += v[j];
  }
#pragma unroll
  for (int off = 32; off > 0; off >>= 1) s += __shfl_xor(s, off, 64);
  if (lane == 0) reds[wave] = s;
  __syncthreads();
  s = reds[0] + reds[1] + reds[2] + reds[3];
  const float inv = 1.f / s;

  u16x8 o;
#pragma unroll
  for (int j = 0; j < 8; ++j) o[j] = __builtin_bit_cast(unsigned short, (bf16)(v[j] * inv));
  *reinterpret_cast<u16x8*>(p + t * 8) = o;
}

// ---------------- launch ----------------
extern "C" void kernel_launch(void* const* d_in, const int* in_sizes, int n_in,
                              void* d_out, int out_size, void* d_ws, size_t ws_size,
                              hipStream_t stream) {
  const float* q = (const float*)d_in[0];
  const float* wq = (const float*)d_in[1];
  const float* wk = (const float*)d_in[2];
  const float* wv = (const float*)d_in[3];
  const float* wo = (const float*)d_in[4];
  float* out = (float*)d_out;

  constexpr int B = 4, S = 2048, D = 1024;
  constexpr long SD = (long)S * D;  // 2,097,152
  constexpr long SS = (long)S * S;  // 4,194,304
  constexpr long DD = (long)D * D;  // 1,048,576

  bf16* wsb = (bf16*)d_ws;
  bf16* qb = wsb;             // B*SD
  bf16* W3 = qb + B * SD;     // 3*DD  (wq;wk;wv stacked rows)
  bf16* wob = W3 + 3 * DD;    // DD
  bf16* Qb = wob + DD;        // B*SD
  bf16* Kb = Qb + B * SD;     // B*SD
  bf16* Vt = Kb + B * SD;     // B*SD, layout [B][D][S]
  bf16* P = Vt + B * SD;      // B*SS
  bf16* X = P + B * SS;       // B*SD, layout [B][D][S] == bugged buffer

  cvt_all<<<3072, 256, 0, stream>>>(q, wq, wk, wv, wo, qb, W3, wob);

  // fused QKV: [8192 x 1024] @ [3072 x 1024]^T -> Qb, Kb, Vt(transposed)
  // 256x128 tile => grid (24,32) = 768 blocks = exactly 3/CU (balanced).
  g256<3, 2><<<dim3(24, 32, 1), 512, 0, stream>>>(qb, W3, Qb, D, 1.f, 0, 0, 0, 0);
  // scores: P[b][i][j] = Q.K/8  (per batch 2048x2048, K=1024), 256 blocks = 1/CU
  g256<0, 4><<<dim3(8, 8, B), 512, 0, stream>>>(Qb, Kb, P, D, 0.125f, SD, SD, SS, S);
  softmax_rows<<<B * S, 256, 0, stream>>>(P);
  // PV as Xt = Vt @ P^T (M=1024, N=2048, K=2048): 256x128 tile =>
  // grid (16,4,4) = 256 blocks = 1/CU (was 128 = half the chip idle).
  g256<0, 2><<<dim3(16, 4, B), 512, 0, stream>>>(Vt, P, X, S, 1.f, SD, SS, SD, S);
  // out = Xflat[8192x1024] @ wo^T -> f32: 256x128 => grid (8,32) = 256 blocks.
  g256<2, 2><<<dim3(8, 32, 1), 512, 0, stream>>>(X, wob, out, D, 1.f, 0, 0, 0, D);
}

// Round 11
// 207.359 us; speedup vs baseline: 1.7759x; 1.0775x over previous
//
#include <hip/hip_runtime.h>
#include <hip/hip_bf16.h>
#include <stdint.h>

typedef __bf16 bf16;
typedef __attribute__((ext_vector_type(8))) __bf16 bf16x8;
typedef __attribute__((ext_vector_type(4))) float f32x4;
typedef __attribute__((ext_vector_type(8))) unsigned short u16x8;

#define LDS_U32 __attribute__((address_space(3))) uint32_t
#define GLB_U32 const __attribute__((address_space(1))) uint32_t
#define GLOAD16(g, l) __builtin_amdgcn_global_load_lds((GLB_U32*)(g), (LDS_U32*)(l), 16, 0, 0)

#define DSR(dst, addr, OFFLIT) \
  asm volatile("ds_read_b128 %0, %1 offset:" OFFLIT : "=v"(dst) : "v"(addr))

#define WAIT_LGKM0() asm volatile("s_waitcnt lgkmcnt(0)")
#define WAIT_VM(n)   asm volatile("s_waitcnt vmcnt(" #n ")")

// ---------------- fused f32 -> bf16 convert (all 5 inputs, one launch) ----------------
__global__ __launch_bounds__(256) void cvt_all(const float* __restrict__ q,
                                               const float* __restrict__ wq,
                                               const float* __restrict__ wk,
                                               const float* __restrict__ wv,
                                               const float* __restrict__ wo,
                                               bf16* __restrict__ qb,
                                               bf16* __restrict__ W3,
                                               bf16* __restrict__ wob) {
  const int b = blockIdx.x;
  const float* src;
  bf16* dst;
  int within;
  if (b < 2048) { src = q; dst = qb; within = b; }
  else {
    const int seg = (b - 2048) >> 8;      // 0..3
    within = (b - 2048) & 255;
    if (seg == 0)      { src = wq; dst = W3; }
    else if (seg == 1) { src = wk; dst = W3 + 1048576; }
    else if (seg == 2) { src = wv; dst = W3 + 2097152; }
    else               { src = wo; dst = wob; }
  }
  const int off = within * 1024;
#pragma unroll
  for (int it = 0; it < 4; ++it) {
    const int j = off + it * 256 + threadIdx.x;
    float4 v = reinterpret_cast<const float4*>(src)[j];
    ushort4 o;
    o.x = __builtin_bit_cast(unsigned short, (bf16)v.x);
    o.y = __builtin_bit_cast(unsigned short, (bf16)v.y);
    o.z = __builtin_bit_cast(unsigned short, (bf16)v.z);
    o.w = __builtin_bit_cast(unsigned short, (bf16)v.w);
    reinterpret_cast<ushort4*>(dst)[j] = o;
  }
}

// ============ 256 x (WN*64) 8-phase GEMM, C = alpha * A @ B^T ============
// Phase efficiency scales with WN (MFMA-per-phase vs fixed barrier/LDS-drain
// cost): WN=4 util ~34%, WN=2 ~20% (r10 measured). Co-residency does NOT
// compose (barrier-lockstepped waves) -> prefer WN=4 at 1 block/CU grids.
// r11: QKV split into QK (WN=4, 256 blocks) + V (WN=2, 256 blocks), both 1/CU.
// EPI: 0 = bf16 C[z*sC+r*ldc+c]; 2 = f32 C[r*ldc+c];
//      4 = Vt scatter: Vt[(r>>11)*2097152 + c*2048 + (r&2047)];
//      5 = QK route: c<1024 -> Qb[r*1024+c], else Kb[r*1024+c-1024].
// LDS: A 32KB (4 units x 8KB) + B WN*8KB, single buffer.
// st_16x32 swizzle both sides. Ring: ph1 B(T+1) x WN; ph2 A{0,2}(T+1);
// boundary A{1,3}(T+1). Waits: end-ph1 vmcnt(WN); boundary vmcnt(2).
template <int EPI, int WN>
__global__ __launch_bounds__(512, 2) void g256(const bf16* __restrict__ A,
                                               const bf16* __restrict__ Bm,
                                               void* __restrict__ Cp,
                                               int K, float alpha,
                                               long sA, long sB, long sC, int ldc) {
  constexpr int BN = WN * 64;
  __shared__ bf16 smem_[(32768 + WN * 8192) / 2];
  const long z = blockIdx.z;
  const int t = threadIdx.x;
  const int l = t & 63;
  const int w = t >> 6;
  const int wr = (w >> 2) * 128;        // wave row base within 256
  const int wc = (w & 3) * (WN * 16);   // wave col base within BN
  const int NT = K >> 6;

  const bf16* Ab = A + z * sA + (long)(blockIdx.y * 256) * K;
  const bf16* Bb = Bm + z * sB + (long)(blockIdx.x * BN) * K;

  // staging inverse map: thread t covers swizzled bytes [t*16, t*16+16) of one
  // 8KB 64-row unit; (r0,c0) = source row/col within the unit.
  uint32_t loc = (uint32_t)t * 16u;
  uint32_t g0 = loc ^ (((loc >> 9) & 1u) << 5);
  const int r0 = (int)(((g0 >> 10) >> 1) * 16 + ((g0 >> 6) & 15));  // 0..63
  const int c0 = (int)(((g0 >> 10) & 1) * 32 + ((g0 & 63) >> 1));   // 0..63

  // per-lane swizzled fragment read offset
  uint32_t lo_ = (uint32_t)((l & 15) * 64 + (l >> 4) * 16);
  const uint32_t lane_off = lo_ ^ (((lo_ >> 9) & 1u) << 5);
  const uint32_t aRegion = (uint32_t)(wr >> 7) * 16384u;
  const uint32_t smem_base = (uint32_t)(size_t)&smem_[0];
  const uint32_t aAddr = smem_base + aRegion + lane_off;

  // per-n B fragment base addresses (row = wc + n*16 within B panel)
  uint32_t bA[WN];
#pragma unroll
  for (int n = 0; n < WN; ++n) {
    const uint32_t row = (uint32_t)(wc + n * 16);
    bA[n] = smem_base + 32768u + (row >> 6) * 8192u + ((row & 63u) >> 4) * 2048u + lane_off;
  }

  auto STAGE1 = [&](const bf16* mat, int unit, int tile, uint32_t isB) {
    uint32_t dst = isB + (uint32_t)unit * 8192u + (uint32_t)t * 16u;
    const bf16* src = mat + (long)(unit * 64 + r0) * K + tile * 64 + c0;
    GLOAD16(src, smem_ + (dst >> 1));
  };

  f32x4 acc[8][WN] = {};

  // ---- prologue: A(0) + B(0) fully staged
  STAGE1(Ab, 0, 0, 0u); STAGE1(Ab, 1, 0, 0u); STAGE1(Ab, 2, 0, 0u); STAGE1(Ab, 3, 0, 0u);
#pragma unroll
  for (int u = 0; u < WN; ++u) STAGE1(Bb, u, 0, 32768u);
  __builtin_amdgcn_sched_barrier(0);
  WAIT_VM(0);
  __builtin_amdgcn_s_barrier();

#define MFMAPH(ph)                                                                   \
  _Pragma("unroll") for (int mi = 0; mi < 2; ++mi)                                   \
  _Pragma("unroll") for (int n = 0; n < WN; ++n)                                     \
  _Pragma("unroll") for (int kk = 0; kk < 2; ++kk)                                   \
    acc[(ph) * 2 + mi][n] = __builtin_amdgcn_mfma_f32_16x16x32_bf16(                 \
        __builtin_bit_cast(bf16x8, aF[mi][kk]), __builtin_bit_cast(bf16x8, bF[n][kk]), \
        acc[(ph) * 2 + mi][n], 0, 0, 0);

  for (int T = 0; T < NT; ++T) {
    f32x4 bF[WN][2];
    f32x4 aF[2][2];

    // ---------- phase 0: all bF (2*WN) + aF quad0 (4); no staging ----------
#pragma unroll
    for (int n = 0; n < WN; ++n) {
      DSR(bF[n][0], bA[n], "0");
      DSR(bF[n][1], bA[n], "1024");
    }
    DSR(aF[0][0], aAddr, "0");    DSR(aF[0][1], aAddr, "1024");
    DSR(aF[1][0], aAddr, "2048"); DSR(aF[1][1], aAddr, "3072");
    __builtin_amdgcn_sched_barrier(0);
    __builtin_amdgcn_s_barrier();
    WAIT_LGKM0();
    __builtin_amdgcn_sched_barrier(0);
    __builtin_amdgcn_s_setprio(1);
    MFMAPH(0)
    __builtin_amdgcn_s_setprio(0);
    __builtin_amdgcn_s_barrier();

    // ---------- phase 1: aF quad1; stage B(T+1); vmcnt(WN) retires A{1,3}(T) ----------
    {
      const uint32_t aP = aAddr + 4096u;
      DSR(aF[0][0], aP, "0");    DSR(aF[0][1], aP, "1024");
      DSR(aF[1][0], aP, "2048"); DSR(aF[1][1], aP, "3072");
      if (T + 1 < NT) {
#pragma unroll
        for (int u = 0; u < WN; ++u) STAGE1(Bb, u, T + 1, 32768u);
      }
      __builtin_amdgcn_sched_barrier(0);
      __builtin_amdgcn_s_barrier();
      WAIT_LGKM0();
      __builtin_amdgcn_sched_barrier(0);
      __builtin_amdgcn_s_setprio(1);
      MFMAPH(1)
      __builtin_amdgcn_s_setprio(0);
      __builtin_amdgcn_sched_barrier(0);
      if (T + 1 < NT) {
        if constexpr (WN == 2) { WAIT_VM(2); }
        else if constexpr (WN == 3) { WAIT_VM(3); }
        else { WAIT_VM(4); }
      } else {
        WAIT_VM(0);
      }
      __builtin_amdgcn_sched_barrier(0);
      __builtin_amdgcn_s_barrier();
    }

    // ---------- phase 2: aF quad2; stage A{0,2}(T+1) ----------
    {
      const uint32_t aP = aAddr + 8192u;
      DSR(aF[0][0], aP, "0");    DSR(aF[0][1], aP, "1024");
      DSR(aF[1][0], aP, "2048"); DSR(aF[1][1], aP, "3072");
      if (T + 1 < NT) { STAGE1(Ab, 0, T + 1, 0u); STAGE1(Ab, 2, T + 1, 0u); }
      __builtin_amdgcn_sched_barrier(0);
      __builtin_amdgcn_s_barrier();
      WAIT_LGKM0();
      __builtin_amdgcn_sched_barrier(0);
      __builtin_amdgcn_s_setprio(1);
      MFMAPH(2)
      __builtin_amdgcn_s_setprio(0);
      __builtin_amdgcn_s_barrier();
    }

    // ---------- phase 3: aF quad3; no staging ----------
    {
      const uint32_t aP = aAddr + 12288u;
      DSR(aF[0][0], aP, "0");    DSR(aF[0][1], aP, "1024");
      DSR(aF[1][0], aP, "2048"); DSR(aF[1][1], aP, "3072");
      __builtin_amdgcn_sched_barrier(0);
      __builtin_amdgcn_s_barrier();
      WAIT_LGKM0();
      __builtin_amdgcn_sched_barrier(0);
      __builtin_amdgcn_s_setprio(1);
      MFMAPH(3)
      __builtin_amdgcn_s_setprio(0);
      __builtin_amdgcn_s_barrier();
    }

    // ---------- boundary: stage A{1,3}(T+1); vmcnt(2) ----------
    if (T + 1 < NT) { STAGE1(Ab, 1, T + 1, 0u); STAGE1(Ab, 3, T + 1, 0u); }
    __builtin_amdgcn_sched_barrier(0);
    if (T + 1 < NT) { WAIT_VM(2); } else { WAIT_VM(0); }
    __builtin_amdgcn_sched_barrier(0);
    __builtin_amdgcn_s_barrier();
  }
#undef MFMAPH

  // ---- epilogue: C/D layout col = lane&15, row = (lane>>4)*4 + i
  const int orow0 = blockIdx.y * 256 + wr + (l >> 4) * 4;
  const int ocol0 = blockIdx.x * BN + wc + (l & 15);
#pragma unroll
  for (int m = 0; m < 8; ++m)
#pragma unroll
    for (int n = 0; n < WN; ++n)
#pragma unroll
      for (int i = 0; i < 4; ++i) {
        const long r = orow0 + m * 16 + i;
        const long c = ocol0 + n * 16;
        const float v = acc[m][n][i] * alpha;
        if constexpr (EPI == 0) {
          ((bf16*)Cp)[z * sC + r * ldc + c] = (bf16)v;
        } else if constexpr (EPI == 2) {
          ((float*)Cp)[r * ldc + c] = v;
        } else if constexpr (EPI == 4) {
          // V-proj -> Vt[b][e][s]: r = b*2048+s, c = e
          ((bf16*)Cp)[(r >> 11) * 2097152 + c * 2048 + (r & 2047)] = (bf16)v;
        } else {
          // QK-proj route: c<1024 -> Q, else K  (rows r = b*2048+s)
          bf16* Qb = (bf16*)Cp;
          bf16* Kb = Qb + 8388608;  // 8192*1024
          if (c < 1024) Qb[r * 1024 + c] = (bf16)v;
          else Kb[r * 1024 + (c - 1024)] = (bf16)v;
        }
      }
}

// ---------------- row softmax, in place, rows of 2048 bf16 ----------------
__global__ __launch_bounds__(256) void softmax_rows(bf16* __restrict__ P) {
  const long row = blockIdx.x;
  bf16* p = P + row * 2048;
  const int t = threadIdx.x;
  const int lane = t & 63;
  const int wave = t >> 6;

  u16x8 raw = *reinterpret_cast<const u16x8*>(p + t * 8);
  float v[8];
#pragma unroll
  for (int j = 0; j < 8; ++j) {
    uint32_t bits = ((uint32_t)raw[j]) << 16;
    v[j] = __builtin_bit_cast(float, bits);
  }
  float m = v[0];
#pragma unroll
  for (int j = 1; j < 8; ++j) m = fmaxf(m, v[j]);
#pragma unroll
  for (int off = 32; off > 0; off >>= 1) m = fmaxf(m, __shfl_xor(m, off, 64));
  __shared__ float redm[4];
  __shared__ float reds[4];
  if (lane == 0) redm[wave] = m;
  __syncthreads();
  m = fmaxf(fmaxf(redm[0], redm[1]), fmaxf(redm[2], redm[3]));

  float s = 0.f;
#pragma unroll
  for (int j = 0; j < 8; ++j) {
    v[j] = __expf(v[j] - m);
    s += v[j];
  }
#pragma unroll
  for (int off = 32; off > 0; off >>= 1) s += __shfl_xor(s, off, 64);
  if (lane == 0) reds[wave] = s;
  __syncthreads();
  s = reds[0] + reds[1] + reds[2] + reds[3];
  const float inv = 1.f / s;

  u16x8 o;
#pragma unroll
  for (int j = 0; j < 8; ++j) o[j] = __builtin_bit_cast(unsigned short, (bf16)(v[j] * inv));
  *reinterpret_cast<u16x8*>(p + t * 8) = o;
}

// ---------------- launch ----------------
extern "C" void kernel_launch(void* const* d_in, const int* in_sizes, int n_in,
                              void* d_out, int out_size, void* d_ws, size_t ws_size,
                              hipStream_t stream) {
  const float* q = (const float*)d_in[0];
  const float* wq = (const float*)d_in[1];
  const float* wk = (const float*)d_in[2];
  const float* wv = (const float*)d_in[3];
  const float* wo = (const float*)d_in[4];
  float* out = (float*)d_out;

  constexpr int B = 4, S = 2048, D = 1024;
  constexpr long SD = (long)S * D;  // 2,097,152
  constexpr long SS = (long)S * S;  // 4,194,304
  constexpr long DD = (long)D * D;  // 1,048,576

  bf16* wsb = (bf16*)d_ws;
  bf16* qb = wsb;             // B*SD
  bf16* W3 = qb + B * SD;     // 3*DD  (wq;wk;wv stacked rows)
  bf16* wob = W3 + 3 * DD;    // DD
  bf16* Qb = wob + DD;        // B*SD
  bf16* Kb = Qb + B * SD;     // B*SD
  bf16* Vt = Kb + B * SD;     // B*SD, layout [B][D][S]
  bf16* P = Vt + B * SD;      // B*SS
  bf16* X = P + B * SS;       // B*SD, layout [B][D][S] == bugged buffer

  cvt_all<<<3072, 256, 0, stream>>>(q, wq, wk, wv, wo, qb, W3, wob);

  // QK-proj: [8192x1024] @ [2048x1024]^T -> Qb,Kb. WN=4, 256 blocks = 1/CU.
  g256<5, 4><<<dim3(8, 32, 1), 512, 0, stream>>>(qb, W3, Qb, D, 1.f, 0, 0, 0, 0);
  // V-proj: [8192x1024] @ [1024x1024]^T -> Vt (transposed). WN=2, 256 blocks.
  g256<4, 2><<<dim3(8, 32, 1), 512, 0, stream>>>(qb, W3 + 2 * DD, Vt, D, 1.f, 0, 0, 0, 0);
  // scores: P[b][i][j] = Q.K/8  (per batch 2048x2048, K=1024), 256 blocks = 1/CU
  g256<0, 4><<<dim3(8, 8, B), 512, 0, stream>>>(Qb, Kb, P, D, 0.125f, SD, SD, SS, S);
  softmax_rows<<<B * S, 256, 0, stream>>>(P);
  // PV as Xt = Vt @ P^T (M=1024, N=2048, K=2048): 256x128 tile, 256 blocks = 1/CU
  g256<0, 2><<<dim3(16, 4, B), 512, 0, stream>>>(Vt, P, X, S, 1.f, SD, SS, SD, S);
  // out = Xflat[8192x1024] @ wo^T -> f32: 256x128, 256 blocks = 1/CU
  g256<2, 2><<<dim3(8, 32, 1), 512, 0, stream>>>(X, wob, out, D, 1.f, 0, 0, 0, D);
}

// Round 12
// 203.673 us; speedup vs baseline: 1.8080x; 1.0181x over previous
//
#include <hip/hip_runtime.h>
#include <hip/hip_bf16.h>
#include <stdint.h>

typedef __bf16 bf16;
typedef __attribute__((ext_vector_type(8))) __bf16 bf16x8;
typedef __attribute__((ext_vector_type(4))) float f32x4;
typedef __attribute__((ext_vector_type(8))) unsigned short u16x8;

#define LDS_U32 __attribute__((address_space(3))) uint32_t
#define GLB_U32 const __attribute__((address_space(1))) uint32_t
#define GLOAD16(g, l) __builtin_amdgcn_global_load_lds((GLB_U32*)(g), (LDS_U32*)(l), 16, 0, 0)

#define DSR(dst, addr, OFFLIT) \
  asm volatile("ds_read_b128 %0, %1 offset:" OFFLIT : "=v"(dst) : "v"(addr))

#define WAIT_LGKM0() asm volatile("s_waitcnt lgkmcnt(0)")
#define WAIT_VM0()   asm volatile("s_waitcnt vmcnt(0)")

// ---------------- fused f32 -> bf16 convert (all 5 inputs, one launch) ----------------
__global__ __launch_bounds__(256) void cvt_all(const float* __restrict__ q,
                                               const float* __restrict__ wq,
                                               const float* __restrict__ wk,
                                               const float* __restrict__ wv,
                                               const float* __restrict__ wo,
                                               bf16* __restrict__ qb,
                                               bf16* __restrict__ W3,
                                               bf16* __restrict__ wob) {
  const int b = blockIdx.x;
  const float* src;
  bf16* dst;
  int within;
  if (b < 2048) { src = q; dst = qb; within = b; }
  else {
    const int seg = (b - 2048) >> 8;      // 0..3
    within = (b - 2048) & 255;
    if (seg == 0)      { src = wq; dst = W3; }
    else if (seg == 1) { src = wk; dst = W3 + 1048576; }
    else if (seg == 2) { src = wv; dst = W3 + 2097152; }
    else               { src = wo; dst = wob; }
  }
  const int off = within * 1024;
#pragma unroll
  for (int it = 0; it < 4; ++it) {
    const int j = off + it * 256 + threadIdx.x;
    float4 v = reinterpret_cast<const float4*>(src)[j];
    ushort4 o;
    o.x = __builtin_bit_cast(unsigned short, (bf16)v.x);
    o.y = __builtin_bit_cast(unsigned short, (bf16)v.y);
    o.z = __builtin_bit_cast(unsigned short, (bf16)v.z);
    o.w = __builtin_bit_cast(unsigned short, (bf16)v.w);
    reinterpret_cast<ushort4*>(dst)[j] = o;
  }
}

// ============ 256 x (WN*64) double-buffered GEMM, C = alpha * A @ B^T ============
// r12: TRUE LDS double-buffer (parity = T&1) -> staging of T+1 goes to the
// other parity with ZERO WAR constraints (its readers finished before the
// previous boundary barrier). This collapses the sync structure from 10
// barriers + 5 waits per K-tile (r11 single-buffer ring) to ONE barrier +
// 2 lgkm + 1 vmcnt per K-tile. r11 measured 6.6 kcyc/K-tile vs ~2 kcyc LDS
// floor: the delta was barrier overhead, which this removes.
// Per K-tile: phase A {read bF(2WN)+aF q0,q1(8); stage B(T+1)+A{0,1}; lgkm0;
// MFMA q0,q1}, phase B {read aF q2,q3 (reuse regs); stage A{2,3}; lgkm0;
// MFMA q2,q3}, then vmcnt(0) + s_barrier.
// LDS layout per parity: A 32KB (4 units x 8KB, 64 rows x 64k) + B WN*8KB;
// parity stride PARB = 32768 + WN*8192. WN=4: 128 KiB total; WN=2: 96 KiB.
// st_16x32 swizzle both sides (linear gload dest + inv-swizzled global src).
// EPI: 0 = bf16 C[z*sC+r*ldc+c]; 2 = f32 C[r*ldc+c];
//      4 = Vt scatter: Vt[(r>>11)*2097152 + c*2048 + (r&2047)];
//      5 = QK route: c<1024 -> Qb[r*1024+c], else Kb[r*1024+c-1024].
template <int EPI, int WN>
__global__ __launch_bounds__(512, 2) void g256(const bf16* __restrict__ A,
                                               const bf16* __restrict__ Bm,
                                               void* __restrict__ Cp,
                                               int K, float alpha,
                                               long sA, long sB, long sC, int ldc) {
  constexpr int BN = WN * 64;
  constexpr uint32_t PARB = 32768u + WN * 8192u;  // parity stride in bytes
  __shared__ bf16 smem_[PARB];                    // 2 parities x PARB bytes
  const long z = blockIdx.z;
  const int t = threadIdx.x;
  const int l = t & 63;
  const int w = t >> 6;
  const int wr = (w >> 2) * 128;        // wave row base within 256
  const int wc = (w & 3) * (WN * 16);   // wave col base within BN
  const int NT = K >> 6;

  const bf16* Ab = A + z * sA + (long)(blockIdx.y * 256) * K;
  const bf16* Bb = Bm + z * sB + (long)(blockIdx.x * BN) * K;

  // staging inverse map: thread t covers swizzled bytes [t*16, t*16+16) of one
  // 8KB 64-row unit; (r0,c0) = source row/col within the unit.
  uint32_t loc = (uint32_t)t * 16u;
  uint32_t g0 = loc ^ (((loc >> 9) & 1u) << 5);
  const int r0 = (int)(((g0 >> 10) >> 1) * 16 + ((g0 >> 6) & 15));  // 0..63
  const int c0 = (int)(((g0 >> 10) & 1) * 32 + ((g0 & 63) >> 1));   // 0..63

  // per-lane swizzled fragment read offset
  uint32_t lo_ = (uint32_t)((l & 15) * 64 + (l >> 4) * 16);
  const uint32_t lane_off = lo_ ^ (((lo_ >> 9) & 1u) << 5);
  const uint32_t aRegion = (uint32_t)(wr >> 7) * 16384u;
  const uint32_t smem_base = (uint32_t)(size_t)&smem_[0];
  const uint32_t aBase = smem_base + aRegion + lane_off;  // + parity + ph*4096

  // per-n B fragment base addresses (row = wc + n*16 within B panel)
  uint32_t bA[WN];
#pragma unroll
  for (int n = 0; n < WN; ++n) {
    const uint32_t row = (uint32_t)(wc + n * 16);
    bA[n] = smem_base + 32768u + (row >> 6) * 8192u + ((row & 63u) >> 4) * 2048u + lane_off;
  }

  // stage one 64-row unit of tile `tile` into parity (tile&1)
  auto STAGE1 = [&](const bf16* mat, int unit, int tile, uint32_t isB) {
    uint32_t dst = (uint32_t)(tile & 1) * PARB + isB + (uint32_t)unit * 8192u + (uint32_t)t * 16u;
    const bf16* src = mat + (long)(unit * 64 + r0) * K + tile * 64 + c0;
    GLOAD16(src, smem_ + (dst >> 1));
  };

  f32x4 acc[8][WN] = {};

  // ---- prologue: A(0) + B(0) into parity 0
  STAGE1(Ab, 0, 0, 0u); STAGE1(Ab, 1, 0, 0u); STAGE1(Ab, 2, 0, 0u); STAGE1(Ab, 3, 0, 0u);
#pragma unroll
  for (int u = 0; u < WN; ++u) STAGE1(Bb, u, 0, 32768u);
  __builtin_amdgcn_sched_barrier(0);
  WAIT_VM0();
  __builtin_amdgcn_s_barrier();

  for (int T = 0; T < NT; ++T) {
    const uint32_t pb = (uint32_t)(T & 1) * PARB;
    const uint32_t aA = aBase + pb;
    f32x4 bF[WN][2];
    f32x4 aF[2][2][2];  // [quad within phase][mi][kk]

    // ========== phase A: bF all + aF quads 0,1; stage B(T+1) + A{0,1} ==========
#pragma unroll
    for (int n = 0; n < WN; ++n) {
      DSR(bF[n][0], bA[n] + pb, "0");
      DSR(bF[n][1], bA[n] + pb, "1024");
    }
    DSR(aF[0][0][0], aA, "0");    DSR(aF[0][0][1], aA, "1024");
    DSR(aF[0][1][0], aA, "2048"); DSR(aF[0][1][1], aA, "3072");
    DSR(aF[1][0][0], aA, "4096"); DSR(aF[1][0][1], aA, "5120");
    DSR(aF[1][1][0], aA, "6144"); DSR(aF[1][1][1], aA, "7168");
    if (T + 1 < NT) {
#pragma unroll
      for (int u = 0; u < WN; ++u) STAGE1(Bb, u, T + 1, 32768u);
      STAGE1(Ab, 0, T + 1, 0u); STAGE1(Ab, 1, T + 1, 0u);
    }
    __builtin_amdgcn_sched_barrier(0);
    WAIT_LGKM0();
    __builtin_amdgcn_sched_barrier(0);
    __builtin_amdgcn_s_setprio(1);
#pragma unroll
    for (int q = 0; q < 2; ++q)
#pragma unroll
      for (int mi = 0; mi < 2; ++mi)
#pragma unroll
        for (int n = 0; n < WN; ++n)
#pragma unroll
          for (int kk = 0; kk < 2; ++kk)
            acc[q * 2 + mi][n] = __builtin_amdgcn_mfma_f32_16x16x32_bf16(
                __builtin_bit_cast(bf16x8, aF[q][mi][kk]), __builtin_bit_cast(bf16x8, bF[n][kk]),
                acc[q * 2 + mi][n], 0, 0, 0);
    __builtin_amdgcn_s_setprio(0);
    __builtin_amdgcn_sched_barrier(0);

    // ========== phase B: aF quads 2,3 (reuse regs); stage A{2,3} ==========
    DSR(aF[0][0][0], aA, "8192");  DSR(aF[0][0][1], aA, "9216");
    DSR(aF[0][1][0], aA, "10240"); DSR(aF[0][1][1], aA, "11264");
    DSR(aF[1][0][0], aA, "12288"); DSR(aF[1][0][1], aA, "13312");
    DSR(aF[1][1][0], aA, "14336"); DSR(aF[1][1][1], aA, "15360");
    if (T + 1 < NT) { STAGE1(Ab, 2, T + 1, 0u); STAGE1(Ab, 3, T + 1, 0u); }
    __builtin_amdgcn_sched_barrier(0);
    WAIT_LGKM0();
    __builtin_amdgcn_sched_barrier(0);
    __builtin_amdgcn_s_setprio(1);
#pragma unroll
    for (int q = 0; q < 2; ++q)
#pragma unroll
      for (int mi = 0; mi < 2; ++mi)
#pragma unroll
        for (int n = 0; n < WN; ++n)
#pragma unroll
          for (int kk = 0; kk < 2; ++kk)
            acc[4 + q * 2 + mi][n] = __builtin_amdgcn_mfma_f32_16x16x32_bf16(
                __builtin_bit_cast(bf16x8, aF[q][mi][kk]), __builtin_bit_cast(bf16x8, bF[n][kk]),
                acc[4 + q * 2 + mi][n], 0, 0, 0);
    __builtin_amdgcn_s_setprio(0);
    __builtin_amdgcn_sched_barrier(0);

    // ========== boundary: T+1 stages must be fully landed & visible ==========
    WAIT_VM0();
    __builtin_amdgcn_s_barrier();
  }

  // ---- epilogue: C/D layout col = lane&15, row = (lane>>4)*4 + i
  const int orow0 = blockIdx.y * 256 + wr + (l >> 4) * 4;
  const int ocol0 = blockIdx.x * BN + wc + (l & 15);
#pragma unroll
  for (int m = 0; m < 8; ++m)
#pragma unroll
    for (int n = 0; n < WN; ++n)
#pragma unroll
      for (int i = 0; i < 4; ++i) {
        const long r = orow0 + m * 16 + i;
        const long c = ocol0 + n * 16;
        const float v = acc[m][n][i] * alpha;
        if constexpr (EPI == 0) {
          ((bf16*)Cp)[z * sC + r * ldc + c] = (bf16)v;
        } else if constexpr (EPI == 2) {
          ((float*)Cp)[r * ldc + c] = v;
        } else if constexpr (EPI == 4) {
          // V-proj -> Vt[b][e][s]: r = b*2048+s, c = e
          ((bf16*)Cp)[(r >> 11) * 2097152 + c * 2048 + (r & 2047)] = (bf16)v;
        } else {
          // QK-proj route: c<1024 -> Q, else K  (rows r = b*2048+s)
          bf16* Qb = (bf16*)Cp;
          bf16* Kb = Qb + 8388608;  // 8192*1024
          if (c < 1024) Qb[r * 1024 + c] = (bf16)v;
          else Kb[r * 1024 + (c - 1024)] = (bf16)v;
        }
      }
}

// ---------------- row softmax, in place, rows of 2048 bf16 ----------------
__global__ __launch_bounds__(256) void softmax_rows(bf16* __restrict__ P) {
  const long row = blockIdx.x;
  bf16* p = P + row * 2048;
  const int t = threadIdx.x;
  const int lane = t & 63;
  const int wave = t >> 6;

  u16x8 raw = *reinterpret_cast<const u16x8*>(p + t * 8);
  float v[8];
#pragma unroll
  for (int j = 0; j < 8; ++j) {
    uint32_t bits = ((uint32_t)raw[j]) << 16;
    v[j] = __builtin_bit_cast(float, bits);
  }
  float m = v[0];
#pragma unroll
  for (int j = 1; j < 8; ++j) m = fmaxf(m, v[j]);
#pragma unroll
  for (int off = 32; off > 0; off >>= 1) m = fmaxf(m, __shfl_xor(m, off, 64));
  __shared__ float redm[4];
  __shared__ float reds[4];
  if (lane == 0) redm[wave] = m;
  __syncthreads();
  m = fmaxf(fmaxf(redm[0], redm[1]), fmaxf(redm[2], redm[3]));

  float s = 0.f;
#pragma unroll
  for (int j = 0; j < 8; ++j) {
    v[j] = __expf(v[j] - m);
    s += v[j];
  }
#pragma unroll
  for (int off = 32; off > 0; off >>= 1) s += __shfl_xor(s, off, 64);
  if (lane == 0) reds[wave] = s;
  __syncthreads();
  s = reds[0] + reds[1] + reds[2] + reds[3];
  const float inv = 1.f / s;

  u16x8 o;
#pragma unroll
  for (int j = 0; j < 8; ++j) o[j] = __builtin_bit_cast(unsigned short, (bf16)(v[j] * inv));
  *reinterpret_cast<u16x8*>(p + t * 8) = o;
}

// ---------------- launch ----------------
extern "C" void kernel_launch(void* const* d_in, const int* in_sizes, int n_in,
                              void* d_out, int out_size, void* d_ws, size_t ws_size,
                              hipStream_t stream) {
  const float* q = (const float*)d_in[0];
  const float* wq = (const float*)d_in[1];
  const float* wk = (const float*)d_in[2];
  const float* wv = (const float*)d_in[3];
  const float* wo = (const float*)d_in[4];
  float* out = (float*)d_out;

  constexpr int B = 4, S = 2048, D = 1024;
  constexpr long SD = (long)S * D;  // 2,097,152
  constexpr long SS = (long)S * S;  // 4,194,304
  constexpr long DD = (long)D * D;  // 1,048,576

  bf16* wsb = (bf16*)d_ws;
  bf16* qb = wsb;             // B*SD
  bf16* W3 = qb + B * SD;     // 3*DD  (wq;wk;wv stacked rows)
  bf16* wob = W3 + 3 * DD;    // DD
  bf16* Qb = wob + DD;        // B*SD
  bf16* Kb = Qb + B * SD;     // B*SD
  bf16* Vt = Kb + B * SD;     // B*SD, layout [B][D][S]
  bf16* P = Vt + B * SD;      // B*SS
  bf16* X = P + B * SS;       // B*SD, layout [B][D][S] == bugged buffer

  cvt_all<<<3072, 256, 0, stream>>>(q, wq, wk, wv, wo, qb, W3, wob);

  // QK-proj: [8192x1024] @ [2048x1024]^T -> Qb,Kb. WN=4, 256 blocks = 1/CU.
  g256<5, 4><<<dim3(8, 32, 1), 512, 0, stream>>>(qb, W3, Qb, D, 1.f, 0, 0, 0, 0);
  // V-proj: [8192x1024] @ [1024x1024]^T -> Vt (transposed). WN=2, 256 blocks.
  g256<4, 2><<<dim3(8, 32, 1), 512, 0, stream>>>(qb, W3 + 2 * DD, Vt, D, 1.f, 0, 0, 0, 0);
  // scores: P[b][i][j] = Q.K/8  (per batch 2048x2048, K=1024), 256 blocks = 1/CU
  g256<0, 4><<<dim3(8, 8, B), 512, 0, stream>>>(Qb, Kb, P, D, 0.125f, SD, SD, SS, S);
  softmax_rows<<<B * S, 256, 0, stream>>>(P);
  // PV as Xt = Vt @ P^T (M=1024, N=2048, K=2048): 256x128 tile, 256 blocks = 1/CU
  g256<0, 2><<<dim3(16, 4, B), 512, 0, stream>>>(Vt, P, X, S, 1.f, SD, SS, SD, S);
  // out = Xflat[8192x1024] @ wo^T -> f32: 256x128, 256 blocks = 1/CU
  g256<2, 2><<<dim3(8, 32, 1), 512, 0, stream>>>(X, wob, out, D, 1.f, 0, 0, 0, D);
}